// Round 4
// baseline (190.265 us; speedup 1.0000x reference)
//
#include <hip/hip_runtime.h>

#define HID 2048
#define OUTN 4096
#define VOC 4096
#define MEMN 4096
#define MDIM 64
#define OPN 5

static __device__ __forceinline__ float wave_reduce(float v) {
    #pragma unroll
    for (int off = 32; off > 0; off >>= 1) v += __shfl_down(v, off, 64);
    return v;
}

// Block-level reduction: 256 threads = 4 waves. (Single use per block.)
static __device__ __forceinline__ float block_reduce(float v, float* red) {
    int lane = threadIdx.x & 63;
    int wid = threadIdx.x >> 6;
    v = wave_reduce(v);
    if (lane == 0) red[wid] = v;
    __syncthreads();
    return red[0] + red[1] + red[2] + red[3];
}

// ---- K1: (a) h_bar[row] = dot(memory[0:64], Wm_w[row]) + Wm_b + hidden0  (wave-0 prologue)
//          (b) s_pre[row] = dot(W_ih[row], x) + b_ih[row] + b_hh[row]      (32 MB stream)
__global__ __launch_bounds__(256) void k1_ih_hbar(
        const float* __restrict__ W_ih,
        const float* __restrict__ x,
        const float* __restrict__ b_ih,
        const float* __restrict__ b_hh,
        const float* __restrict__ Wm_w,
        const float* __restrict__ Wm_b,
        const float* __restrict__ memory,
        const float* __restrict__ hidden0,
        float* __restrict__ h_bar,
        float* __restrict__ s_pre) {
    __shared__ float red[4];
    int row = blockIdx.x;
    int tid = threadIdx.x;

    // (a) wave 0 computes h_bar[row]
    if (tid < 64) {
        float v = Wm_w[(size_t)row * MDIM + tid] * memory[tid];
        v = wave_reduce(v);
        if (tid == 0) h_bar[row] = v + Wm_b[row] + hidden0[row];
    }

    // (b) full block computes the VOC-length dot
    const float* wrow = W_ih + (size_t)row * VOC;
    float acc = 0.f;
    #pragma unroll
    for (int p = 0; p < VOC / (256 * 4); ++p) {   // 4 passes
        int k = (p * 256 + tid) * 4;
        float4 w  = *(const float4*)(wrow + k);
        float4 xv = *(const float4*)(x + k);
        acc += w.x * xv.x + w.y * xv.y + w.z * xv.z + w.w * xv.w;
    }
    float s = block_reduce(acc, red);
    if (tid == 0) s_pre[row] = s + b_ih[row] + b_hh[row];
}

// ---- K2: h[row] = tanh(s_pre[row] + dot(W_hh[row], h_bar))   (16 MB stream)
__global__ __launch_bounds__(256) void k2_hidden(
        const float* __restrict__ W_hh,
        const float* __restrict__ h_bar,
        const float* __restrict__ s_pre,
        float* __restrict__ h,
        float* __restrict__ ht_out) {
    __shared__ float red[4];
    int row = blockIdx.x;
    int tid = threadIdx.x;
    const float* wrow = W_hh + (size_t)row * HID;
    float acc = 0.f;
    #pragma unroll
    for (int p = 0; p < HID / (256 * 4); ++p) {   // 2 passes
        int k = (p * 256 + tid) * 4;
        float4 w  = *(const float4*)(wrow + k);
        float4 hv = *(const float4*)(h_bar + k);
        acc += w.x * hv.x + w.y * hv.y + w.z * hv.z + w.w * hv.w;
    }
    float s = block_reduce(acc, red);
    if (tid == 0) {
        float hv = tanhf(s + s_pre[row]);
        h[row] = hv;
        ht_out[row] = hv;
    }
}

// ---- K3: STENCIL blocks FIRST (bid < STB), then 4096 Wy head blocks.
// Stencil block j handles 1024 elems (16 rows, 1 float4/thread); redundantly
// computes the 5 Wa logits (40 KB L2-hot). Block 0 also computes the 64 Wn
// dots for new_elt (its slice contains row 0). wa/new_elt never hit global.
#define STB 256
__global__ __launch_bounds__(256) void k3_heads_mem(
        const float* __restrict__ Wy_w,
        const float* __restrict__ Wy_b,
        const float* __restrict__ Wn_w,
        const float* __restrict__ Wn_b,
        const float* __restrict__ Wa_w,
        const float* __restrict__ Wa_b,
        const float* __restrict__ h,
        const float* __restrict__ memory,
        float* __restrict__ out_f,
        float* __restrict__ mem_f) {
    __shared__ float red[4];
    __shared__ float sm[MDIM + OPN];   // new_elt [0:64) (block 0 only), wa logits [64:69)
    int bid = blockIdx.x;
    int tid = threadIdx.x;

    if (bid >= STB) {
        // ---- output head row
        int row = bid - STB;
        const float* wrow = Wy_w + (size_t)row * HID;
        float acc = 0.f;
        #pragma unroll
        for (int p = 0; p < HID / (256 * 4); ++p) {   // 2 passes
            int k = (p * 256 + tid) * 4;
            float4 w  = *(const float4*)(wrow + k);
            float4 hv = *(const float4*)(h + k);
            acc += w.x * hv.x + w.y * hv.y + w.z * hv.z + w.w * hv.w;
        }
        float s = block_reduce(acc, red);
        if (tid == 0) out_f[row] = 1.f / (1.f + expf(-(s + Wy_b[row])));
        return;
    }

    // ---- stencil block
    int lane = tid & 63;
    int wid = tid >> 6;

    // 5 Wa logits, wave-per-row (wave 0 takes rows 0 and 4)
    for (int r = wid; r < OPN; r += 4) {
        const float* wrow = Wa_w + (size_t)r * HID;
        float acc = 0.f;
        #pragma unroll
        for (int p = 0; p < HID / (64 * 4); ++p) {    // 8 float4 per lane
            int k = (p * 64 + lane) * 4;
            float4 w  = *(const float4*)(wrow + k);
            float4 hv = *(const float4*)(h + k);
            acc += w.x * hv.x + w.y * hv.y + w.z * hv.z + w.w * hv.w;
        }
        acc = wave_reduce(acc);
        if (lane == 0) sm[MDIM + r] = acc + Wa_b[r];
    }
    // block 0 only: 64 Wn dots -> new_elt (sigmoid) in LDS
    if (bid == 0) {
        for (int r = wid; r < MDIM; r += 4) {
            const float* wrow = Wn_w + (size_t)r * HID;
            float acc = 0.f;
            #pragma unroll
            for (int p = 0; p < HID / (64 * 4); ++p) {
                int k = (p * 64 + lane) * 4;
                float4 w  = *(const float4*)(wrow + k);
                float4 hv = *(const float4*)(h + k);
                acc += w.x * hv.x + w.y * hv.y + w.z * hv.z + w.w * hv.w;
            }
            acc = wave_reduce(acc);
            if (lane == 0) sm[r] = 1.f / (1.f + expf(-(acc + Wn_b[r])));
        }
    }
    __syncthreads();

    // softmax over the 5 logits (per thread; LDS broadcast reads)
    float l0 = sm[MDIM + 0], l1 = sm[MDIM + 1], l2 = sm[MDIM + 2],
          l3 = sm[MDIM + 3], l4 = sm[MDIM + 4];
    float mx = fmaxf(fmaxf(fmaxf(l0, l1), fmaxf(l2, l3)), l4);
    float e0 = expf(l0 - mx), e1 = expf(l1 - mx), e2 = expf(l2 - mx),
          e3 = expf(l3 - mx), e4 = expf(l4 - mx);
    float inv = 1.f / (e0 + e1 + e2 + e3 + e4);
    float a0 = e0 * inv, a1 = e1 * inv, a2 = e2 * inv, a3 = e3 * inv,
          a4 = e4 * inv;

    // 1024 elements per block = 1 float4 per thread (16 rows per block)
    int e = bid * 1024 + tid * 4;
    int r = e >> 6, c = e & (MDIM - 1);
    const float4 mc = *(const float4*)(memory + e);
    const float4 mp = *(const float4*)(memory + (((r + 1) & (MEMN - 1)) << 6) + c);
    const float4 mm = *(const float4*)(memory + (((r - 1) & (MEMN - 1)) << 6) + c);
    float cp = a0 + (r < MEMN - 1 ? a4 : 0.f);
    float cm = a1 + (r > 0 ? a3 : 0.f);
    float4 o;
    o.x = cp * mp.x + cm * mm.x + a2 * mc.x;
    o.y = cp * mp.y + cm * mm.y + a2 * mc.y;
    o.z = cp * mp.z + cm * mm.z + a2 * mc.z;
    o.w = cp * mp.w + cm * mm.w + a2 * mc.w;
    if (r == 0) {
        o.x += sm[c + 0];
        o.y += sm[c + 1];
        o.z += sm[c + 2];
        o.w += sm[c + 3];
    }
    *(float4*)(mem_f + e) = o;
}

extern "C" void kernel_launch(void* const* d_in, const int* in_sizes, int n_in,
                              void* d_out, int out_size, void* d_ws, size_t ws_size,
                              hipStream_t stream) {
    const float* input   = (const float*)d_in[0];
    const float* hidden0 = (const float*)d_in[1];
    const float* memory  = (const float*)d_in[2];
    const float* W_ih    = (const float*)d_in[3];
    const float* b_ih    = (const float*)d_in[4];
    const float* W_hh    = (const float*)d_in[5];
    const float* b_hh    = (const float*)d_in[6];
    const float* Wm_w    = (const float*)d_in[7];
    const float* Wm_b    = (const float*)d_in[8];
    const float* Wy_w    = (const float*)d_in[9];
    const float* Wy_b    = (const float*)d_in[10];
    const float* Wn_w    = (const float*)d_in[11];
    const float* Wn_b    = (const float*)d_in[12];
    const float* Wa_w    = (const float*)d_in[13];
    const float* Wa_b    = (const float*)d_in[14];

    float* ws    = (float*)d_ws;
    float* h_bar = ws;          // 2048
    float* s_pre = ws + 2048;   // 2048
    float* h     = ws + 4096;   // 2048

    float* out_f = (float*)d_out;              // 4096
    float* ht_f  = (float*)d_out + OUTN;       // 2048
    float* mem_f = (float*)d_out + OUTN + HID; // 262144

    k1_ih_hbar<<<HID, 256, 0, stream>>>(W_ih, input, b_ih, b_hh,
                                        Wm_w, Wm_b, memory, hidden0,
                                        h_bar, s_pre);
    k2_hidden<<<HID, 256, 0, stream>>>(W_hh, h_bar, s_pre, h, ht_f);
    k3_heads_mem<<<STB + OUTN, 256, 0, stream>>>(Wy_w, Wy_b, Wn_w, Wn_b,
                                                 Wa_w, Wa_b, h, memory,
                                                 out_f, mem_f);
}

// Round 5
// 138.846 us; speedup vs baseline: 1.3703x; 1.3703x over previous
//
#include <hip/hip_runtime.h>

#define HID 2048
#define OUTN 4096
#define VOC 4096
#define MEMN 4096
#define MDIM 64
#define OPN 5

static __device__ __forceinline__ float wave_reduce(float v) {
    #pragma unroll
    for (int off = 32; off > 0; off >>= 1) v += __shfl_down(v, off, 64);
    return v;
}

// Block-level reduction: 256 threads = 4 waves. (Single use per block.)
static __device__ __forceinline__ float block_reduce(float v, float* red) {
    int lane = threadIdx.x & 63;
    int wid = threadIdx.x >> 6;
    v = wave_reduce(v);
    if (lane == 0) red[wid] = v;
    __syncthreads();
    return red[0] + red[1] + red[2] + red[3];
}

// ---- K1: (a) h_bar[row] = dot(memory[0:64], Wm_w[row]) + Wm_b + hidden0  (wave-0 prologue)
//          (b) s_pre[row] = dot(W_ih[row], x) + b_ih[row] + b_hh[row]      (32 MB stream)
// One block per row; (a) and (b) independent, no sync between them. [proven round 3]
__global__ __launch_bounds__(256) void k1_ih_hbar(
        const float* __restrict__ W_ih,
        const float* __restrict__ x,
        const float* __restrict__ b_ih,
        const float* __restrict__ b_hh,
        const float* __restrict__ Wm_w,
        const float* __restrict__ Wm_b,
        const float* __restrict__ memory,
        const float* __restrict__ hidden0,
        float* __restrict__ h_bar,
        float* __restrict__ s_pre) {
    __shared__ float red[4];
    int row = blockIdx.x;
    int tid = threadIdx.x;

    // (a) wave 0 computes h_bar[row]
    if (tid < 64) {
        float v = Wm_w[(size_t)row * MDIM + tid] * memory[tid];
        v = wave_reduce(v);
        if (tid == 0) h_bar[row] = v + Wm_b[row] + hidden0[row];
    }

    // (b) full block computes the VOC-length dot
    const float* wrow = W_ih + (size_t)row * VOC;
    float acc = 0.f;
    #pragma unroll
    for (int p = 0; p < VOC / (256 * 4); ++p) {   // 4 passes
        int k = (p * 256 + tid) * 4;
        float4 w  = *(const float4*)(wrow + k);
        float4 xv = *(const float4*)(x + k);
        acc += w.x * xv.x + w.y * xv.y + w.z * xv.z + w.w * xv.w;
    }
    float s = block_reduce(acc, red);
    if (tid == 0) s_pre[row] = s + b_ih[row] + b_hh[row];
}

// ---- K2: h[row] = tanh(s_pre[row] + dot(W_hh[row], h_bar))   (16 MB stream) [proven round 3]
__global__ __launch_bounds__(256) void k2_hidden(
        const float* __restrict__ W_hh,
        const float* __restrict__ h_bar,
        const float* __restrict__ s_pre,
        float* __restrict__ h,
        float* __restrict__ ht_out) {
    __shared__ float red[4];
    int row = blockIdx.x;
    int tid = threadIdx.x;
    const float* wrow = W_hh + (size_t)row * HID;
    float acc = 0.f;
    #pragma unroll
    for (int p = 0; p < HID / (256 * 4); ++p) {   // 2 passes
        int k = (p * 256 + tid) * 4;
        float4 w  = *(const float4*)(wrow + k);
        float4 hv = *(const float4*)(h_bar + k);
        acc += w.x * hv.x + w.y * hv.y + w.z * hv.z + w.w * hv.w;
    }
    float s = block_reduce(acc, red);
    if (tid == 0) {
        float hv = tanhf(s + s_pre[row]);
        h[row] = hv;
        ht_out[row] = hv;
    }
}

// ---- K3: fused output heads, one block per row. [proven round 0]
// rows [0,4096): output = sigmoid(h.Wy+b) -> out
// rows [4096,4160): new_elt = sigmoid(h.Wn+b) -> ws
// rows [4160,4165): wa logits = h.Wa+b -> ws
__global__ __launch_bounds__(256) void k_heads(
        const float* __restrict__ Wy_w,
        const float* __restrict__ Wy_b,
        const float* __restrict__ Wn_w,
        const float* __restrict__ Wn_b,
        const float* __restrict__ Wa_w,
        const float* __restrict__ Wa_b,
        const float* __restrict__ h,
        float* __restrict__ out,
        float* __restrict__ new_elt,
        float* __restrict__ wa_logits) {
    __shared__ float red[4];
    int row = blockIdx.x;
    int tid = threadIdx.x;
    const float* wrow;
    if (row < OUTN)             wrow = Wy_w + (size_t)row * HID;
    else if (row < OUTN + MDIM) wrow = Wn_w + (size_t)(row - OUTN) * HID;
    else                        wrow = Wa_w + (size_t)(row - OUTN - MDIM) * HID;
    float acc = 0.f;
    #pragma unroll
    for (int p = 0; p < HID / (256 * 4); ++p) {   // 2 passes
        int k = (p * 256 + tid) * 4;
        float4 w  = *(const float4*)(wrow + k);
        float4 hv = *(const float4*)(h + k);
        acc += w.x * hv.x + w.y * hv.y + w.z * hv.z + w.w * hv.w;
    }
    float s = block_reduce(acc, red);
    if (tid == 0) {
        if (row < OUTN) {
            out[row] = 1.f / (1.f + expf(-(s + Wy_b[row])));
        } else if (row < OUTN + MDIM) {
            int r = row - OUTN;
            new_elt[r] = 1.f / (1.f + expf(-(s + Wn_b[r])));
        } else {
            int r = row - OUTN - MDIM;
            wa_logits[r] = s + Wa_b[r];
        }
    }
}

// ---- K4: memory stencil update + softmax(a) recomputed per thread. [proven round 0]
__global__ __launch_bounds__(256) void k_mem(
        const float* __restrict__ m,
        const float* __restrict__ wa,
        const float* __restrict__ new_elt,
        float* __restrict__ mem_out) {
    int idx = blockIdx.x * blockDim.x + threadIdx.x;
    if (idx >= MEMN * MDIM) return;
    float l0 = wa[0], l1 = wa[1], l2 = wa[2], l3 = wa[3], l4 = wa[4];
    float mx = fmaxf(fmaxf(fmaxf(l0, l1), fmaxf(l2, l3)), l4);
    float e0 = expf(l0 - mx), e1 = expf(l1 - mx), e2 = expf(l2 - mx),
          e3 = expf(l3 - mx), e4 = expf(l4 - mx);
    float inv = 1.f / (e0 + e1 + e2 + e3 + e4);
    float a0 = e0 * inv, a1 = e1 * inv, a2 = e2 * inv, a3 = e3 * inv, a4 = e4 * inv;

    int r = idx >> 6, c = idx & (MDIM - 1);
    float mc = m[idx];
    float mp = m[(size_t)((r + 1) & (MEMN - 1)) * MDIM + c];
    float mm = m[(size_t)((r - 1) & (MEMN - 1)) * MDIM + c];
    float cp = a0 + (r < MEMN - 1 ? a4 : 0.f);
    float cm = a1 + (r > 0 ? a3 : 0.f);
    float v = cp * mp + cm * mm + a2 * mc;
    if (r == 0) v += new_elt[c];
    mem_out[idx] = v;
}

extern "C" void kernel_launch(void* const* d_in, const int* in_sizes, int n_in,
                              void* d_out, int out_size, void* d_ws, size_t ws_size,
                              hipStream_t stream) {
    const float* input   = (const float*)d_in[0];
    const float* hidden0 = (const float*)d_in[1];
    const float* memory  = (const float*)d_in[2];
    const float* W_ih    = (const float*)d_in[3];
    const float* b_ih    = (const float*)d_in[4];
    const float* W_hh    = (const float*)d_in[5];
    const float* b_hh    = (const float*)d_in[6];
    const float* Wm_w    = (const float*)d_in[7];
    const float* Wm_b    = (const float*)d_in[8];
    const float* Wy_w    = (const float*)d_in[9];
    const float* Wy_b    = (const float*)d_in[10];
    const float* Wn_w    = (const float*)d_in[11];
    const float* Wn_b    = (const float*)d_in[12];
    const float* Wa_w    = (const float*)d_in[13];
    const float* Wa_b    = (const float*)d_in[14];

    float* ws      = (float*)d_ws;
    float* h_bar   = ws;          // 2048
    float* s_pre   = ws + 2048;   // 2048
    float* h       = ws + 4096;   // 2048
    float* wa      = ws + 6144;   // 5 (pad 8)
    float* new_elt = ws + 6152;   // 64

    float* out_f = (float*)d_out;              // 4096
    float* ht_f  = (float*)d_out + OUTN;       // 2048
    float* mem_f = (float*)d_out + OUTN + HID; // 262144

    k1_ih_hbar<<<HID, 256, 0, stream>>>(W_ih, input, b_ih, b_hh,
                                        Wm_w, Wm_b, memory, hidden0,
                                        h_bar, s_pre);
    k2_hidden<<<HID, 256, 0, stream>>>(W_hh, h_bar, s_pre, h, ht_f);
    int rows3 = OUTN + MDIM + OPN;
    k_heads<<<rows3, 256, 0, stream>>>(Wy_w, Wy_b, Wn_w, Wn_b,
                                       Wa_w, Wa_b, h, out_f,
                                       new_elt, wa);
    k_mem<<<(MEMN * MDIM) / 256, 256, 0, stream>>>(memory, wa, new_elt, mem_f);
}